// Round 1
// 659.081 us; speedup vs baseline: 1.1917x; 1.1917x over previous
//
#include <hip/hip_runtime.h>
#include <hip/hip_bf16.h>
#include <stdint.h>

#define D_IN   4096
#define D_OUT  4096
#define MROWS  8192   // B*S = 4*2048
#define CAPN   1024
#define NT     64     // K tiles of 64

typedef __bf16 bf16x8 __attribute__((ext_vector_type(8)));
typedef float f32x4 __attribute__((ext_vector_type(4)));

// ---------- async global->LDS helper (16B per lane, uniform LDS base) ----------
__device__ static inline void async_copy16(const void* g, void* l) {
  __builtin_amdgcn_global_load_lds((__attribute__((address_space(1))) void*)g,
                                   (__attribute__((address_space(3))) void*)l,
                                   16, 0, 0);
}

// ---------- x fp32 -> bf16 ----------
__global__ __launch_bounds__(256) void cvt_x_kernel(const float* __restrict__ x,
                                                    __hip_bfloat16* __restrict__ xb) {
  size_t i = ((size_t)blockIdx.x * 256 + threadIdx.x) * 8;
  float4 f0 = *(const float4*)(x + i);
  float4 f1 = *(const float4*)(x + i + 4);
  union { __hip_bfloat16 h[8]; uint4 u; } o;
  o.h[0] = __float2bfloat16(f0.x); o.h[1] = __float2bfloat16(f0.y);
  o.h[2] = __float2bfloat16(f0.z); o.h[3] = __float2bfloat16(f0.w);
  o.h[4] = __float2bfloat16(f1.x); o.h[5] = __float2bfloat16(f1.y);
  o.h[6] = __float2bfloat16(f1.z); o.h[7] = __float2bfloat16(f1.w);
  *(uint4*)(xb + i) = o.u;
}

// ---------- dequant W: bf16(wl[o][i] * scale[o]) ----------
__global__ __launch_bounds__(256) void cvt_w_kernel(const float* __restrict__ wl,
                                                    const float* __restrict__ wscale,
                                                    __hip_bfloat16* __restrict__ wb) {
  size_t i = ((size_t)blockIdx.x * 256 + threadIdx.x) * 8;
  int row = (int)(i >> 12);             // D_IN = 4096 per row
  float s = wscale[row];
  float4 f0 = *(const float4*)(wl + i);
  float4 f1 = *(const float4*)(wl + i + 4);
  union { __hip_bfloat16 h[8]; uint4 u; } o;
  o.h[0] = __float2bfloat16(f0.x * s); o.h[1] = __float2bfloat16(f0.y * s);
  o.h[2] = __float2bfloat16(f0.z * s); o.h[3] = __float2bfloat16(f0.w * s);
  o.h[4] = __float2bfloat16(f1.x * s); o.h[5] = __float2bfloat16(f1.y * s);
  o.h[6] = __float2bfloat16(f1.z * s); o.h[7] = __float2bfloat16(f1.w * s);
  *(uint4*)(wb + i) = o.u;
}

// ---------- logits[c] = mem_keys[c,:] . q  (q = x[0,0,:], fp32) ----------
__global__ __launch_bounds__(256) void mem_logits_kernel(const float* __restrict__ keys,
                                                         const float* __restrict__ q,
                                                         float* __restrict__ logits) {
  int c = blockIdx.x;
  const float* k = keys + (size_t)c * D_IN;
  float p = 0.f;
  for (int i = threadIdx.x; i < D_IN; i += 256) p += k[i] * q[i];
  for (int off = 32; off; off >>= 1) p += __shfl_down(p, off);
  __shared__ float r[4];
  if ((threadIdx.x & 63) == 0) r[threadIdx.x >> 6] = p;
  __syncthreads();
  if (threadIdx.x == 0) logits[c] = r[0] + r[1] + r[2] + r[3];
}

// ---------- fused softmax(logits) + memo[o] = attn @ vals ----------
// 64 blocks x 256 threads. Each block redundantly computes the full softmax
// from the 1024 logits (4 KB, trivial), then its 64-output slice: 4 c-groups
// of 256 caps per thread-group, LDS-combined. No memset, no atomics.
__global__ __launch_bounds__(256) void mem_attn_out_kernel(const float* __restrict__ logits,
                                                           const float* __restrict__ vals,
                                                           float* __restrict__ memo) {
  int tid = threadIdx.x;
  __shared__ float sa[1024];
  __shared__ float wm[4], ws[4];
  __shared__ float part[4][64];
  float4 lv = ((const float4*)logits)[tid];
  float m = fmaxf(fmaxf(lv.x, lv.y), fmaxf(lv.z, lv.w));
  for (int off = 32; off; off >>= 1) m = fmaxf(m, __shfl_down(m, off));
  if ((tid & 63) == 0) wm[tid >> 6] = m;
  __syncthreads();
  m = fmaxf(fmaxf(wm[0], wm[1]), fmaxf(wm[2], wm[3]));
  float e0 = __expf(lv.x - m), e1 = __expf(lv.y - m);
  float e2 = __expf(lv.z - m), e3 = __expf(lv.w - m);
  float s = e0 + e1 + e2 + e3;
  for (int off = 32; off; off >>= 1) s += __shfl_down(s, off);
  if ((tid & 63) == 0) ws[tid >> 6] = s;
  __syncthreads();
  float inv = 1.f / (ws[0] + ws[1] + ws[2] + ws[3]);
  sa[tid * 4 + 0] = e0 * inv; sa[tid * 4 + 1] = e1 * inv;
  sa[tid * 4 + 2] = e2 * inv; sa[tid * 4 + 3] = e3 * inv;
  __syncthreads();
  int g = tid >> 6, lane = tid & 63;
  int o = blockIdx.x * 64 + lane;
  float acc = 0.f;
  const float* vp = vals + (size_t)(g * 256) * D_OUT + o;
#pragma unroll 8
  for (int c = 0; c < 256; ++c) acc += sa[g * 256 + c] * vp[(size_t)c * D_OUT];
  part[g][lane] = acc;
  __syncthreads();
  if (tid < 64) memo[o] = part[0][lane] + part[1][lane] + part[2][lane] + part[3][lane];
}

// ---------- main GEMM: 256x256 tile, BK=64, 8 waves, 8-phase schedule ----------
// LDS: fragment-major chunks. Chunk = one 16-row tile x one k-half (kk):
//   A chunk c (c = mt*2+kk): lane l holds A[mblk + mt*16 + (l&15)][T*64 + kk*32 + (l>>4)*8 ..+8]
// ds_read is lane-linear -> conflict-free; stage via global_load_lds with per-lane
// global source in fragment order (LDS dest linear per wave).
// Phase schedule per K-tile T (buffer b = T&1):
//   ph0: read a[0..3][kk] (A-half0, 8 rds) + b[0..1][kk] (B-half0, 4 rds); stage A1(T+1)->b^1
//   ph1: read b[2..3][kk] (B-half1, 4 rds);                               stage A0(T+2)->b
//   ph2: read a[4..7][kk] (A-half1, 8 rds);                               stage B0(T+2)->b
//   ph3: no reads;                                                        stage B1(T+2)->b
//   each phase: barrier; lgkmcnt(0); setprio(1); 16 MFMA (one C-quadrant); setprio(0); barrier
//   vmcnt(6) once per tile (before ph3's barrier) -> 3 newest half-tiles stay in flight;
//   guarantees A1(T+1) + everything older landed => tile T+1 fully staged.
__global__ __launch_bounds__(512, 2) void gemm_8ph_kernel(const __hip_bfloat16* __restrict__ A,
                                                          const __hip_bfloat16* __restrict__ Bm,
                                                          const float* __restrict__ memo,
                                                          float* __restrict__ C) {
  __shared__ bf16x8 LA[2][32][64];   // 64 KiB
  __shared__ bf16x8 LB[2][32][64];   // 64 KiB
  const int tid = threadIdx.x;
  const int l = tid & 63;
  const int w = tid >> 6;            // 0..7
  const int wr = w >> 2;             // 0..1  (m)
  const int wc = w & 3;              // 0..3  (n)
  const int w2 = w * 2;

  // XCD-aware swizzle (nwg = 512, 512 % 8 == 0 -> simple bijective form)
  const int bid = blockIdx.x;
  const int swz = (bid & 7) * 64 + (bid >> 3);
  const int m_blk = (swz >> 4) * 256;   // 32 m-tiles
  const int n_blk = (swz & 15) * 256;   // 16 n-tiles

  const int lm = l & 15;
  const int lk = (l >> 4) * 8;

  // staging sources: wave w stages chunks {h*16 + w*2, h*16 + w*2 + 1} of each half h.
  // chunk c = h*16 + w*2 + i  ->  mt = h*8 + w (indep. of i), kk = i.
  const __hip_bfloat16* baseA0 = A  + (size_t)(m_blk + (0 * 8 + w) * 16 + lm) * D_IN + lk;
  const __hip_bfloat16* baseA1 = A  + (size_t)(m_blk + (1 * 8 + w) * 16 + lm) * D_IN + lk;
  const __hip_bfloat16* baseB0 = Bm + (size_t)(n_blk + (0 * 8 + w) * 16 + lm) * D_IN + lk;
  const __hip_bfloat16* baseB1 = Bm + (size_t)(n_blk + (1 * 8 + w) * 16 + lm) * D_IN + lk;

#define STAGE_A(h, T, sb) do {                                                   \
    async_copy16(baseA##h + (size_t)(T) * 64,      &LA[sb][(h) * 16 + w2][0]);   \
    async_copy16(baseA##h + (size_t)(T) * 64 + 32, &LA[sb][(h) * 16 + w2 + 1][0]); \
  } while (0)
#define STAGE_B(h, T, sb) do {                                                   \
    async_copy16(baseB##h + (size_t)(T) * 64,      &LB[sb][(h) * 16 + w2][0]);   \
    async_copy16(baseB##h + (size_t)(T) * 64 + 32, &LB[sb][(h) * 16 + w2 + 1][0]); \
  } while (0)

  f32x4 acc[8][4] = {};
  bf16x8 a[4][2], b[4][2];

#define BAR_MFMA(JH, IH)                                                         \
  do {                                                                           \
    __builtin_amdgcn_s_barrier();                                                \
    asm volatile("s_waitcnt lgkmcnt(0)" ::: "memory");                           \
    __builtin_amdgcn_sched_barrier(0);                                           \
    __builtin_amdgcn_s_setprio(1);                                               \
    _Pragma("unroll") for (int jj = 0; jj < 4; ++jj)                             \
    _Pragma("unroll") for (int i2 = 0; i2 < 2; ++i2)                             \
    _Pragma("unroll") for (int kk = 0; kk < 2; ++kk)                             \
      acc[(JH) * 4 + jj][(IH) * 2 + i2] = __builtin_amdgcn_mfma_f32_16x16x32_bf16( \
          a[jj][kk], b[(IH) * 2 + i2][kk], acc[(JH) * 4 + jj][(IH) * 2 + i2], 0, 0, 0); \
    __builtin_amdgcn_s_setprio(0);                                               \
    __builtin_amdgcn_sched_barrier(0);                                           \
    __builtin_amdgcn_s_barrier();                                                \
  } while (0)

// one K-tile (4 phases). bb: buffer literal. DOS1: stage A1(t+1); DOS2: stage (t+2).
// VMSTMT: vmcnt statement placed before ph3's barrier.
#define TILE4(t, bb, DOS1, DOS2, VMSTMT)                                         \
  do {                                                                           \
    /* ph0 */                                                                    \
    _Pragma("unroll") for (int j = 0; j < 4; ++j) {                              \
      a[j][0] = LA[bb][(2 * j + wr) * 2 + 0][l];                                 \
      a[j][1] = LA[bb][(2 * j + wr) * 2 + 1][l];                                 \
    }                                                                            \
    _Pragma("unroll") for (int ii = 0; ii < 2; ++ii) {                           \
      b[ii][0] = LB[bb][(4 * ii + wc) * 2 + 0][l];                               \
      b[ii][1] = LB[bb][(4 * ii + wc) * 2 + 1][l];                               \
    }                                                                            \
    if (DOS1) { STAGE_A(1, (t) + 1, (bb) ^ 1); }                                 \
    BAR_MFMA(0, 0);                                                              \
    /* ph1 */                                                                    \
    _Pragma("unroll") for (int ii = 2; ii < 4; ++ii) {                           \
      b[ii][0] = LB[bb][(4 * ii + wc) * 2 + 0][l];                               \
      b[ii][1] = LB[bb][(4 * ii + wc) * 2 + 1][l];                               \
    }                                                                            \
    if (DOS2) { STAGE_A(0, (t) + 2, bb); }                                       \
    BAR_MFMA(0, 1);                                                              \
    /* ph2 */                                                                    \
    _Pragma("unroll") for (int j = 0; j < 4; ++j) {                              \
      a[j][0] = LA[bb][(2 * j + 8 + wr) * 2 + 0][l];                             \
      a[j][1] = LA[bb][(2 * j + 8 + wr) * 2 + 1][l];                             \
    }                                                                            \
    if (DOS2) { STAGE_B(0, (t) + 2, bb); }                                       \
    BAR_MFMA(1, 0);                                                              \
    /* ph3 */                                                                    \
    if (DOS2) { STAGE_B(1, (t) + 2, bb); }                                       \
    VMSTMT;                                                                      \
    BAR_MFMA(1, 1);                                                              \
  } while (0)

#define VM6 asm volatile("s_waitcnt vmcnt(6)" ::: "memory")
#define VM0 asm volatile("s_waitcnt vmcnt(0)" ::: "memory")
#define VMN ((void)0)

  // prologue: issue 7 half-tiles in steady-state order, then require tile 0 landed
  STAGE_A(0, 0, 0); STAGE_B(0, 0, 0); STAGE_B(1, 0, 0); STAGE_A(1, 0, 0);
  STAGE_A(0, 1, 1); STAGE_B(0, 1, 1); STAGE_B(1, 1, 1);
  asm volatile("s_waitcnt vmcnt(6)" ::: "memory");
  __builtin_amdgcn_s_barrier();

#pragma unroll 1
  for (int t = 0; t < NT - 2; t += 2) {   // tiles 0..61: all guards statically true
    TILE4(t, 0, 1, 1, VM6);
    TILE4(t + 1, 1, 1, 1, VM6);
  }
  TILE4(NT - 2, 0, 1, 0, VM0);            // tile 62: stage A1(63) only; drain
  TILE4(NT - 1, 1, 0, 0, VMN);            // tile 63: compute only

  // epilogue: D mapping col = l&15, row = (l>>4)*4 + r
  const int col_l = l & 15;
  const int row_l = (l >> 4) * 4;
#pragma unroll
  for (int ii = 0; ii < 4; ++ii) {
    int col = n_blk + (4 * ii + wc) * 16 + col_l;
    float mo = 0.01f * memo[col];
#pragma unroll
    for (int j = 0; j < 8; ++j) {
      int row = m_blk + (2 * j + wr) * 16 + row_l;
      float* cp = C + (size_t)row * D_OUT + col;
#pragma unroll
      for (int r = 0; r < 4; ++r) cp[(size_t)r * D_OUT] = acc[j][ii][r] + mo;
    }
  }
}

extern "C" void kernel_launch(void* const* d_in, const int* in_sizes, int n_in,
                              void* d_out, int out_size, void* d_ws, size_t ws_size,
                              hipStream_t stream) {
  const float* x   = (const float*)d_in[0];   // [4,2048,4096]
  const float* wl  = (const float*)d_in[1];   // [4096,4096]
  const float* wsc = (const float*)d_in[2];   // [4096,1]
  const float* mk  = (const float*)d_in[3];   // [1024,4096]
  const float* mv  = (const float*)d_in[4];   // [1024,4096]
  float* out = (float*)d_out;                 // [4,2048,4096] fp32

  char* wsb = (char*)d_ws;
  __hip_bfloat16* xb = (__hip_bfloat16*)wsb;                                    // 67,108,864 B
  __hip_bfloat16* wb = (__hip_bfloat16*)(wsb + (size_t)MROWS * D_IN * 2);       // 33,554,432 B
  float* logits = (float*)(wsb + (size_t)MROWS * D_IN * 2 + (size_t)D_OUT * D_IN * 2);
  float* memo = logits + CAPN;                                                  // 4096 floats

  // conversions
  cvt_x_kernel<<<dim3((MROWS * D_IN) / 2048), dim3(256), 0, stream>>>(x, xb);
  cvt_w_kernel<<<dim3((D_OUT * D_IN) / 2048), dim3(256), 0, stream>>>(wl, wsc, wb);

  // associative-memory path (q = x[0,0,:], fp32 throughout)
  mem_logits_kernel<<<dim3(CAPN), dim3(256), 0, stream>>>(mk, x, logits);
  mem_attn_out_kernel<<<dim3(D_OUT / 64), dim3(256), 0, stream>>>(logits, mv, memo);

  // main GEMM + fused memory_out epilogue: 512 blocks x 512 threads
  gemm_8ph_kernel<<<dim3((MROWS / 256) * (D_OUT / 256)), dim3(512), 0, stream>>>(xb, wb, memo, out);
}